// Round 4
// baseline (101.735 us; speedup 1.0000x reference)
//
#include <hip/hip_runtime.h>
#include <math.h>

constexpr int BDIM   = 1024;
constexpr int INDIM  = 512;
constexpr int OUTDIM = 512;

constexpr int NG  = 4;              // in-block k-split groups (one wave-pair each)
constexpr int KCH = INDIM / NG;     // 128 k per group
constexpr int BK  = 16;             // staged k per chunk
constexpr int BB  = 64;             // batch rows per block (= lanes of a wave)
constexpr int CW  = 8;              // outputs per wave
constexpr int TOW = 16;             // outputs per block (2 o-waves)
constexpr int XPAD = 20;            // x row stride in floats (16B-aligned rows, spread banks)
constexpr int XS_G = BB * XPAD;     // 1280 floats of x staging per group
constexpr int PSTR = BB * TOW;      // 1024 floats per partial plane
constexpr int SMEM_FLOATS = NG * 3 * PSTR;   // 12288 floats = 48 KiB (>= NG*XS_G = 5120)

__global__ void prep_k(const float* __restrict__ wh1, const float* __restrict__ mh1,
                       const float* __restrict__ wh2, const float* __restrict__ mh2,
                       float* __restrict__ W1, float* __restrict__ W2) {
    int e = blockIdx.x * 256 + threadIdx.x;
    if (e >= INDIM * OUTDIM) return;
    W1[e] = tanhf(wh1[e]) * (1.0f / (1.0f + expf(-mh1[e])));
    W2[e] = tanhf(wh2[e]) * (1.0f / (1.0f + expf(-mh2[e])));
}

__global__ __launch_bounds__(512, 6) void main_k(
    const float* __restrict__ X, const float* __restrict__ W1,
    const float* __restrict__ W2, const float* __restrict__ G1,
    float* __restrict__ out)
{
    __shared__ __align__(16) float smem[SMEM_FLOATS];

    const int t    = threadIdx.x;
    const int wave = __builtin_amdgcn_readfirstlane(t >> 6);  // 0..7, provably uniform
    const int lane = t & 63;                                   // = batch row within tile
    const int g    = wave >> 1;                                // k-group 0..3
    const int ow   = wave & 1;                                 // o-wave 0..1
    const int o0   = blockIdx.x * TOW;
    const int b0   = blockIdx.y * BB;
    const int oB   = o0 + ow * CW;                             // wave's 8-output base (uniform)

    float* xs = smem + g * XS_G;

    float a1[CW] = {};
    float lm[CW] = {};
    float pr[CW];
    #pragma unroll
    for (int o = 0; o < CW; ++o) pr[o] = 1.0f;

    // staging role: 128 threads per group stage that group's 64x16 x-tile
    const int lt = t & 127;
    const int sb = lt >> 1;            // batch row 0..63
    const int sk = (lt & 1) * 8;       // k offset 0 or 8

    for (int kc0 = 0; kc0 < KCH; kc0 += BK) {
        const int k0 = g * KCH + kc0;
        {
            const float4 v0 = *reinterpret_cast<const float4*>(&X[(b0 + sb) * INDIM + k0 + sk]);
            const float4 v1 = *reinterpret_cast<const float4*>(&X[(b0 + sb) * INDIM + k0 + sk + 4]);
            *reinterpret_cast<float4*>(&xs[sb * XPAD + sk])     = v0;
            *reinterpret_cast<float4*>(&xs[sb * XPAD + sk + 4]) = v1;
        }
        __syncthreads();

        #pragma unroll
        for (int kc = 0; kc < BK; kc += 4) {
            const float4 xv = *reinterpret_cast<const float4*>(&xs[lane * XPAD + kc]);
            const float xarr[4] = {xv.x, xv.y, xv.z, xv.w};
            #pragma unroll
            for (int j = 0; j < 4; ++j) {
                const int k = k0 + kc + j;
                const float x = xarr[j];
                const float l = log2f(fmaxf(fabsf(x), 1e-7f));
                const float s = (x > 0.f) ? 0.f : ((x < 0.f) ? -2.f : -1.f);
                const float* w1r = W1 + k * OUTDIM + oB;   // uniform address -> s_load
                const float* w2r = W2 + k * OUTDIM + oB;   // uniform address -> s_load
                #pragma unroll
                for (int o = 0; o < CW; ++o) {
                    const float w1v = w1r[o];
                    const float w2v = w2r[o];
                    const float swv = fabsf(W2[(oB + o) * OUTDIM + k]);  // abs folds to modifier
                    a1[o] = fmaf(x, w1v, a1[o]);
                    lm[o] = fmaf(l, w2v, lm[o]);
                    pr[o] *= fmaf(s, swv, 1.0f);
                }
            }
        }
        __syncthreads();
    }

    // ---- dump per-group partials (x staging dead after final barrier; region aliased)
    {
        float* pa = smem + (g * 3 + 0) * PSTR;
        float* pl = smem + (g * 3 + 1) * PSTR;
        float* pp = smem + (g * 3 + 2) * PSTR;
        const int base = lane * TOW + ow * CW;
        #pragma unroll
        for (int o = 0; o < CW; o += 4) {
            *reinterpret_cast<float4*>(&pa[base + o]) = float4{a1[o], a1[o+1], a1[o+2], a1[o+3]};
            *reinterpret_cast<float4*>(&pl[base + o]) = float4{lm[o], lm[o+1], lm[o+2], lm[o+3]};
            *reinterpret_cast<float4*>(&pp[base + o]) = float4{pr[o], pr[o+1], pr[o+2], pr[o+3]};
        }
    }
    __syncthreads();

    // ---- combine across groups + epilogue: 512 threads x 2 outputs
    {
        const int idx2 = t * 2;
        const int b  = idx2 >> 4;      // 0..63
        const int oc = idx2 & 15;      // even
        float A0 = 0.f, A1 = 0.f, L0 = 0.f, L1 = 0.f, P0 = 1.f, P1 = 1.f;
        #pragma unroll
        for (int gg = 0; gg < NG; ++gg) {
            const float2 a = *reinterpret_cast<const float2*>(&smem[(gg * 3 + 0) * PSTR + b * TOW + oc]);
            const float2 l = *reinterpret_cast<const float2*>(&smem[(gg * 3 + 1) * PSTR + b * TOW + oc]);
            const float2 p = *reinterpret_cast<const float2*>(&smem[(gg * 3 + 2) * PSTR + b * TOW + oc]);
            A0 += a.x; A1 += a.y;
            L0 += l.x; L1 += l.y;
            P0 *= p.x; P1 *= p.y;
        }
        const float2 gv = *reinterpret_cast<const float2*>(&G1[o0 + oc]);
        const float g0  = 1.0f / (1.0f + expf(-gv.x));
        const float g1v = 1.0f / (1.0f + expf(-gv.y));
        constexpr float CAP = 28.853900817779268f;   // 20 * log2(e)
        const float m0 = exp2f(fminf(L0, CAP));
        const float m1 = exp2f(fminf(L1, CAP));
        const float s0 = fminf(fmaxf(P0, -1.0f), 1.0f);
        const float s1 = fminf(fmaxf(P1, -1.0f), 1.0f);
        float2 r;
        r.x = g0  * A0 + (1.0f - g0)  * m0 * s0;
        r.y = g1v * A1 + (1.0f - g1v) * m1 * s1;
        *reinterpret_cast<float2*>(&out[(b0 + b) * OUTDIM + o0 + oc]) = r;
    }
}

extern "C" void kernel_launch(void* const* d_in, const int* in_sizes, int n_in,
                              void* d_out, int out_size, void* d_ws, size_t ws_size,
                              hipStream_t stream) {
    const float* X   = (const float*)d_in[0];
    const float* wh1 = (const float*)d_in[1];
    const float* mh1 = (const float*)d_in[2];
    const float* wh2 = (const float*)d_in[3];
    const float* mh2 = (const float*)d_in[4];
    const float* G1  = (const float*)d_in[5];
    float* out = (float*)d_out;
    float* W1  = (float*)d_ws;
    float* W2  = W1 + INDIM * OUTDIM;

    prep_k<<<dim3((INDIM * OUTDIM + 255) / 256), 256, 0, stream>>>(wh1, mh1, wh2, mh2, W1, W2);
    main_k<<<dim3(OUTDIM / TOW, BDIM / BB), 512, 0, stream>>>(X, W1, W2, G1, out);
}

// Round 7
// 52.745 us; speedup vs baseline: 1.9288x; 1.9288x over previous
//
#include <hip/hip_runtime.h>
#include <math.h>

constexpr int BDIM   = 1024;
constexpr int INDIM  = 512;
constexpr int OUTDIM = 512;

constexpr int NG  = 4;              // k-slices = waves per block
constexpr int KCH = INDIM / NG;     // 128 k per slice
constexpr int BK  = 32;             // k per staged chunk
constexpr int BT  = 16;             // batch rows per block
constexpr int TO  = 64;             // outputs per block

constexpr int XROW  = BT * 4 + 4;   // 68 floats: row-quads + pad (breaks bank alias)
constexpr int XWAVE = BK * XROW;    // 2176 floats per wave-private x region
constexpr int PART_FLOATS = NG * 3 * BT * TO;  // 12288 floats = 48 KiB (> NG*XWAVE = 8704)

// prep: pack per-(k,o) weight quad {W1[k,o], W2[k,o], |W2flat[o*512+k]|, 0}
__global__ void prep_k(const float* __restrict__ wh1, const float* __restrict__ mh1,
                       const float* __restrict__ wh2, const float* __restrict__ mh2,
                       float4* __restrict__ wq) {
    int e = blockIdx.x * 256 + threadIdx.x;
    if (e >= INDIM * OUTDIM) return;
    int k = e >> 9, o = e & 511;
    int et = o * INDIM + k;
    float w1 = tanhf(wh1[e])  * (1.0f / (1.0f + expf(-mh1[e])));
    float w2 = tanhf(wh2[e])  * (1.0f / (1.0f + expf(-mh2[e])));
    float sw = fabsf(tanhf(wh2[et]) * (1.0f / (1.0f + expf(-mh2[et]))));
    wq[e] = float4{w1, w2, sw, 0.0f};
}

__global__ __launch_bounds__(256, 2) void main_k(
    const float* __restrict__ X, const float4* __restrict__ wq,
    const float* __restrict__ G1, float* __restrict__ out)
{
    __shared__ __align__(16) float smem[PART_FLOATS];

    const int t     = threadIdx.x;
    const int w     = t >> 6;          // k-slice 0..3 (one wave each)
    const int lane  = t & 63;
    const int o_sub = lane & 15;       // 16 output groups
    const int r_sub = lane >> 4;       // 4 row groups
    const int o0    = blockIdx.x * TO;
    const int b0    = blockIdx.y * BT;

    float* xw = smem + w * XWAVE;      // wave-private x staging

    float accA[4][4] = {};
    float accL[4][4] = {};
    float accP[4][4];
    #pragma unroll
    for (int ri = 0; ri < 4; ++ri)
        #pragma unroll
        for (int oi = 0; oi < 4; ++oi) accP[ri][oi] = 1.0f;

    // stager mapping (within wave): 16 rows x 32 k, 8 consecutive k per lane
    const int srow = lane >> 2;
    const int sk8  = (lane & 3) * 8;
    const int kbase = w * KCH;

    // prefetch first chunk
    float4 ga = *reinterpret_cast<const float4*>(&X[(b0 + srow) * INDIM + kbase + sk8]);
    float4 gb = *reinterpret_cast<const float4*>(&X[(b0 + srow) * INDIM + kbase + sk8 + 4]);

    for (int c0 = 0; c0 < KCH; c0 += BK) {
        const int kg = kbase + c0;
        // derive + LDS write
        {
            const float xa[8] = {ga.x, ga.y, ga.z, ga.w, gb.x, gb.y, gb.z, gb.w};
            #pragma unroll
            for (int j = 0; j < 8; ++j) {
                const float x = xa[j];
                const float l = log2f(fmaxf(fabsf(x), 1e-7f));
                const float s = (x > 0.f) ? 0.f : ((x < 0.f) ? -2.f : -1.f);
                *reinterpret_cast<float4*>(&xw[(sk8 + j) * XROW + srow * 4]) = float4{x, l, s, 0.f};
            }
        }
        // prefetch next chunk's X (latency hidden under inner loop)
        if (c0 + BK < KCH) {
            ga = *reinterpret_cast<const float4*>(&X[(b0 + srow) * INDIM + kg + BK + sk8]);
            gb = *reinterpret_cast<const float4*>(&X[(b0 + srow) * INDIM + kg + BK + sk8 + 4]);
        }
        __syncthreads();   // LDS writes visible before reads

        #pragma unroll 4
        for (int kk = 0; kk < BK; ++kk) {
            const float4* wrow = wq + (kg + kk) * OUTDIM + o0;   // FIX: include block output base
            // weights via VMEM (L1/L2-hot), 16-way lane-collapsed, imm offsets
            const float4 wv0 = wrow[o_sub];
            const float4 wv1 = wrow[o_sub + 16];
            const float4 wv2 = wrow[o_sub + 32];
            const float4 wv3 = wrow[o_sub + 48];
            // x via LDS broadcast quads
            const float4 xv0 = *reinterpret_cast<const float4*>(&xw[kk * XROW + (r_sub * 4 + 0) * 4]);
            const float4 xv1 = *reinterpret_cast<const float4*>(&xw[kk * XROW + (r_sub * 4 + 1) * 4]);
            const float4 xv2 = *reinterpret_cast<const float4*>(&xw[kk * XROW + (r_sub * 4 + 2) * 4]);
            const float4 xv3 = *reinterpret_cast<const float4*>(&xw[kk * XROW + (r_sub * 4 + 3) * 4]);
            const float4 xv[4] = {xv0, xv1, xv2, xv3};
            const float4 wv[4] = {wv0, wv1, wv2, wv3};
            #pragma unroll
            for (int ri = 0; ri < 4; ++ri) {
                #pragma unroll
                for (int oi = 0; oi < 4; ++oi) {
                    accA[ri][oi] = fmaf(xv[ri].x, wv[oi].x, accA[ri][oi]);
                    accL[ri][oi] = fmaf(xv[ri].y, wv[oi].y, accL[ri][oi]);
                    accP[ri][oi] *= fmaf(xv[ri].z, wv[oi].z, 1.0f);
                }
            }
        }
        __syncthreads();   // all reads done before next chunk's writes
    }

    // ---- dump per-wave partials (x staging dead; region aliased)
    {
        #pragma unroll
        for (int ri = 0; ri < 4; ++ri) {
            const int row = r_sub * 4 + ri;
            #pragma unroll
            for (int oi = 0; oi < 4; ++oi) {
                const int o = o_sub + 16 * oi;
                smem[((w * 3 + 0) * BT + row) * TO + o] = accA[ri][oi];
                smem[((w * 3 + 1) * BT + row) * TO + o] = accL[ri][oi];
                smem[((w * 3 + 2) * BT + row) * TO + o] = accP[ri][oi];
            }
        }
    }
    __syncthreads();

    // combine 4 slices + epilogue: 256 threads x 4 outputs
    {
        const int row = t >> 4;
        const int oc  = (t & 15) * 4;
        float A[4] = {0, 0, 0, 0}, L[4] = {0, 0, 0, 0}, P[4] = {1, 1, 1, 1};
        #pragma unroll
        for (int s = 0; s < NG; ++s) {
            const float4 a = *reinterpret_cast<const float4*>(&smem[((s * 3 + 0) * BT + row) * TO + oc]);
            const float4 l = *reinterpret_cast<const float4*>(&smem[((s * 3 + 1) * BT + row) * TO + oc]);
            const float4 p = *reinterpret_cast<const float4*>(&smem[((s * 3 + 2) * BT + row) * TO + oc]);
            A[0] += a.x; A[1] += a.y; A[2] += a.z; A[3] += a.w;
            L[0] += l.x; L[1] += l.y; L[2] += l.z; L[3] += l.w;
            P[0] *= p.x; P[1] *= p.y; P[2] *= p.z; P[3] *= p.w;
        }
        const float4 gv = *reinterpret_cast<const float4*>(&G1[o0 + oc]);
        const float garr[4] = {gv.x, gv.y, gv.z, gv.w};
        constexpr float CAP = 28.853900817779268f;   // 20 * log2(e)
        float4 r;
        float* rp = &r.x;
        #pragma unroll
        for (int j = 0; j < 4; ++j) {
            const float g = 1.0f / (1.0f + expf(-garr[j]));
            const float m = exp2f(fminf(L[j], CAP));
            const float s = fminf(fmaxf(P[j], -1.0f), 1.0f);
            rp[j] = g * A[j] + (1.0f - g) * m * s;
        }
        *reinterpret_cast<float4*>(&out[(b0 + row) * OUTDIM + o0 + oc]) = r;
    }
}

extern "C" void kernel_launch(void* const* d_in, const int* in_sizes, int n_in,
                              void* d_out, int out_size, void* d_ws, size_t ws_size,
                              hipStream_t stream) {
    const float* X   = (const float*)d_in[0];
    const float* wh1 = (const float*)d_in[1];
    const float* mh1 = (const float*)d_in[2];
    const float* wh2 = (const float*)d_in[3];
    const float* mh2 = (const float*)d_in[4];
    const float* G1  = (const float*)d_in[5];
    float* out = (float*)d_out;
    float4* wq = (float4*)d_ws;   // 512*512*16B = 4 MiB

    prep_k<<<dim3((INDIM * OUTDIM + 255) / 256), 256, 0, stream>>>(wh1, mh1, wh2, mh2, wq);
    main_k<<<dim3(OUTDIM / TO, BDIM / BT), 256, 0, stream>>>(X, wq, G1, out);
}